// Round 6
// baseline (621.889 us; speedup 1.0000x reference)
//
#include <hip/hip_runtime.h>
#include <hip/hip_bf16.h>

// WindowAttention: B_=4096 windows, N=64 tokens, C=256, H=8 heads, hd=32.
// One WG (512 thr, 8 waves) per window; wave h owns head h end-to-end.
// q/k/v/P fragment transposes are IN-REGISTER via a 2-stage __shfl_xor
// butterfly (validated primitive; replaces r5's ds_bpermute suspect).
// LDS holds only x (bf16) and attn_out => 66 KB => 2 WGs/CU, 4 waves/SIMD.
// Phase 1 runs as 3 register-light passes (q, k, v) to fit the 128-VGPR
// budget of __launch_bounds__(512,4). Biases enter as MFMA C-in; k and its
// bias are pre-scaled by 1/sqrt(d) in prep.

typedef __attribute__((ext_vector_type(8))) short bf16x8;   // 8 bf16 = 4 VGPR
typedef __attribute__((ext_vector_type(4))) float f32x4;    // MFMA acc

struct alignas(8) us4 { unsigned short x, y, z, w; };

__device__ inline unsigned short f2bf(float f) {
    unsigned u = __builtin_bit_cast(unsigned, f);
    u += 0x7fffu + ((u >> 16) & 1u);
    return (unsigned short)(u >> 16);
}

__device__ inline unsigned pack2(float lo, float hi) {   // dword (lo16, hi16)
    return (unsigned)f2bf(lo) | ((unsigned)f2bf(hi) << 16);
}

__device__ inline f32x4 mfma16(bf16x8 a, bf16x8 b, f32x4 c) {
    return __builtin_amdgcn_mfma_f32_16x16x32_bf16(a, b, c, 0, 0, 0);
}

__device__ inline bf16x8 lds8(const unsigned short* p) {
    return *reinterpret_cast<const bf16x8*>(p);
}

// One butterfly stage: swap lane-bit (distance D) with reg-bit1 of V[0..3].
// new[lB,r1,r0] = old[lB'=r1, r1'=lB, r0].
__device__ inline void bfly_stage(unsigned V[4], int D, bool b) {
    unsigned t0 = (unsigned)__shfl_xor((int)V[0], D);
    unsigned t1 = (unsigned)__shfl_xor((int)V[1], D);
    unsigned t2 = (unsigned)__shfl_xor((int)V[2], D);
    unsigned t3 = (unsigned)__shfl_xor((int)V[3], D);
    V[0] = b ? t2 : V[0];
    V[1] = b ? t3 : V[1];
    V[2] = b ? V[2] : t0;
    V[3] = b ? V[3] : t1;
}

// Full cross-g transpose: T[g1 g0 | w1 w0] = V[g0 w1 | g1 w0]
// = Op(xor32: l1<->r1) then Op(xor16: l0<->r1). Element-verified.
__device__ inline bf16x8 bfly4(unsigned v0, unsigned v1, unsigned v2,
                               unsigned v3, int lane) {
    unsigned V[4] = { v0, v1, v2, v3 };
    bfly_stage(V, 32, (lane & 32) != 0);
    bfly_stage(V, 16, (lane & 16) != 0);
    uint4 r = { V[0], V[1], V[2], V[3] };
    return __builtin_bit_cast(bf16x8, r);
}

// ---------------- prep: weight casts (+k prescale) + dense bias gather ------
__global__ void prep_kernel(const float* __restrict__ qkv_w,
                            const float* __restrict__ proj_w,
                            const float* __restrict__ bias_table,
                            const int*   __restrict__ rel_index,
                            unsigned short* __restrict__ qkv_wb,
                            unsigned short* __restrict__ proj_wb,
                            float* __restrict__ biasF) {
    const float scale = 0.1767766952966369f;   // 1/sqrt(32)
    int stride = gridDim.x * blockDim.x;
    int t0 = blockIdx.x * blockDim.x + threadIdx.x;
    for (int i = t0; i < 768 * 256; i += stride) {
        float w = qkv_w[i];
        int row = i >> 8;
        if (row >= 256 && row < 512) w *= scale;   // k rows pre-scaled
        qkv_wb[i] = f2bf(w);
    }
    for (int i = t0; i < 256 * 256; i += stride) proj_wb[i] = f2bf(proj_w[i]);
    for (int i = t0; i < 8 * 64 * 64; i += stride) {
        int h = i >> 12, rem = i & 4095, m = rem >> 6, n = rem & 63;
        biasF[i] = bias_table[rel_index[m * 64 + n] * 8 + h];
    }
}

// ---------------- fused window attention ------------------------------------
// LDS (ushort units), 33792 us = 67584 B:
//   XB @ 0     : x bf16 [64][264]
//   AO @ 16896 : attn_out bf16 [64][264]
__global__ __launch_bounds__(512, 4) void win_attn_kernel(
    const float* __restrict__ x,
    const float* __restrict__ qkv_b,
    const float* __restrict__ proj_b,
    const unsigned short* __restrict__ qkv_wb,
    const unsigned short* __restrict__ proj_wb,
    const float* __restrict__ biasF,
    float* __restrict__ out)
{
    __shared__ unsigned short sm[33792];
    const int AO   = 16896;
    const int tid  = threadIdx.x;
    const int wid  = tid >> 6;         // 0..7 = head
    const int lane = tid & 63;
    const int r16  = lane & 15;
    const int g    = lane >> 4;
    const int h    = wid;
    const int win  = blockIdx.x;

    const float* bh = biasF + h * 4096;
    const f32x4 zero4 = {0.f, 0.f, 0.f, 0.f};

    // ---- stage x -> XB (bf16) ----
    const float* xg = x + (size_t)win * 16384;
#pragma unroll
    for (int i = 0; i < 8; ++i) {
        int flat = i * 2048 + tid * 4;
        float4 v = *reinterpret_cast<const float4*>(xg + flat);
        us4 pk = { f2bf(v.x), f2bf(v.y), f2bf(v.z), f2bf(v.w) };
        *reinterpret_cast<us4*>(&sm[(flat >> 8) * 264 + (flat & 255)]) = pk;
    }
    __syncthreads();                                   // B0: XB ready

    // ---- Phase 1a: q pass (swapped: A=Wq, B=x -> D[ch][token]) ----
    unsigned qp[4][2][2];
    {
        f32x4 acc[4][2];
#pragma unroll
        for (int t = 0; t < 4; ++t)
#pragma unroll
            for (int dt = 0; dt < 2; ++dt) {
                f32x4 ci;
#pragma unroll
                for (int j = 0; j < 4; ++j)
                    ci[j] = qkv_b[(2 * h + dt) * 16 + g * 4 + j];
                acc[t][dt] = ci;
            }
#pragma unroll
        for (int ks = 0; ks < 8; ++ks) {
            bf16x8 xf[4];
#pragma unroll
            for (int t = 0; t < 4; ++t)
                xf[t] = lds8(&sm[(t * 16 + r16) * 264 + ks * 32 + g * 8]);
            bf16x8 w0 = *reinterpret_cast<const bf16x8*>(
                qkv_wb + ((2 * h + 0) * 16 + r16) * 256 + ks * 32 + g * 8);
            bf16x8 w1 = *reinterpret_cast<const bf16x8*>(
                qkv_wb + ((2 * h + 1) * 16 + r16) * 256 + ks * 32 + g * 8);
#pragma unroll
            for (int t = 0; t < 4; ++t) {
                acc[t][0] = mfma16(w0, xf[t], acc[t][0]);
                acc[t][1] = mfma16(w1, xf[t], acc[t][1]);
            }
        }
#pragma unroll
        for (int t = 0; t < 4; ++t)
#pragma unroll
            for (int dt = 0; dt < 2; ++dt) {
                qp[t][dt][0] = pack2(acc[t][dt][0], acc[t][dt][1]);
                qp[t][dt][1] = pack2(acc[t][dt][2], acc[t][dt][3]);
            }
    }

    // ---- Phase 1b: k pass (swapped; weights+bias pre-scaled) ----
    unsigned kp[4][2][2];
    {
        f32x4 acc[4][2];
#pragma unroll
        for (int t = 0; t < 4; ++t)
#pragma unroll
            for (int dt = 0; dt < 2; ++dt) {
                f32x4 ci;
#pragma unroll
                for (int j = 0; j < 4; ++j)
                    ci[j] = qkv_b[256 + (2 * h + dt) * 16 + g * 4 + j]
                            * 0.1767766952966369f;
                acc[t][dt] = ci;
            }
#pragma unroll
        for (int ks = 0; ks < 8; ++ks) {
            bf16x8 xf[4];
#pragma unroll
            for (int t = 0; t < 4; ++t)
                xf[t] = lds8(&sm[(t * 16 + r16) * 264 + ks * 32 + g * 8]);
            bf16x8 w0 = *reinterpret_cast<const bf16x8*>(
                qkv_wb + ((16 + 2 * h + 0) * 16 + r16) * 256 + ks * 32 + g * 8);
            bf16x8 w1 = *reinterpret_cast<const bf16x8*>(
                qkv_wb + ((16 + 2 * h + 1) * 16 + r16) * 256 + ks * 32 + g * 8);
#pragma unroll
            for (int t = 0; t < 4; ++t) {
                acc[t][0] = mfma16(w0, xf[t], acc[t][0]);
                acc[t][1] = mfma16(w1, xf[t], acc[t][1]);
            }
        }
#pragma unroll
        for (int t = 0; t < 4; ++t)
#pragma unroll
            for (int dt = 0; dt < 2; ++dt) {
                kp[t][dt][0] = pack2(acc[t][dt][0], acc[t][dt][1]);
                kp[t][dt][1] = pack2(acc[t][dt][2], acc[t][dt][3]);
            }
    }

    // ---- Phase 1c: v pass (normal: D[token][ch]) ----
    unsigned vp[4][2][2];
    {
        f32x4 acc[4][2];
#pragma unroll
        for (int t = 0; t < 4; ++t)
#pragma unroll
            for (int dt = 0; dt < 2; ++dt) {
                float vb = qkv_b[512 + (2 * h + dt) * 16 + r16];
                f32x4 ci = { vb, vb, vb, vb };
                acc[t][dt] = ci;
            }
#pragma unroll
        for (int ks = 0; ks < 8; ++ks) {
            bf16x8 xf[4];
#pragma unroll
            for (int t = 0; t < 4; ++t)
                xf[t] = lds8(&sm[(t * 16 + r16) * 264 + ks * 32 + g * 8]);
            bf16x8 w0 = *reinterpret_cast<const bf16x8*>(
                qkv_wb + ((32 + 2 * h + 0) * 16 + r16) * 256 + ks * 32 + g * 8);
            bf16x8 w1 = *reinterpret_cast<const bf16x8*>(
                qkv_wb + ((32 + 2 * h + 1) * 16 + r16) * 256 + ks * 32 + g * 8);
#pragma unroll
            for (int t = 0; t < 4; ++t) {
                acc[t][0] = mfma16(xf[t], w0, acc[t][0]);
                acc[t][1] = mfma16(xf[t], w1, acc[t][1]);
            }
        }
#pragma unroll
        for (int t = 0; t < 4; ++t)
#pragma unroll
            for (int dt = 0; dt < 2; ++dt) {
                vp[t][dt][0] = pack2(acc[t][dt][0], acc[t][dt][1]);
                vp[t][dt][1] = pack2(acc[t][dt][2], acc[t][dt][3]);
            }
    }

    // ---- K fragments (A-operand of swapped QK^T): lane r16 = key token ----
    bf16x8 ak[4];
#pragma unroll
    for (int t = 0; t < 4; ++t)
        ak[t] = bfly4(kp[t][0][0], kp[t][0][1], kp[t][1][0], kp[t][1][1], lane);

    // ---- Phase 2: per query-tile c: QK^T (+bias C-in), softmax, P frags ----
    bf16x8 ap[4][2];
#pragma unroll
    for (int c = 0; c < 4; ++c) {
        bf16x8 bqc = bfly4(qp[c][0][0], qp[c][0][1], qp[c][1][0], qp[c][1][1],
                           lane);
        f32x4 stc[4];
#pragma unroll
        for (int rt = 0; rt < 4; ++rt) {
            float4 b4 = *reinterpret_cast<const float4*>(
                bh + (c * 16 + r16) * 64 + rt * 16 + g * 4);
            f32x4 ci = { b4.x, b4.y, b4.z, b4.w };
            stc[rt] = mfma16(ak[rt], bqc, ci);
        }
        float mx = -1e30f;
#pragma unroll
        for (int rt = 0; rt < 4; ++rt)
#pragma unroll
            for (int j = 0; j < 4; ++j) mx = fmaxf(mx, stc[rt][j]);
        mx = fmaxf(mx, __shfl_xor(mx, 16));
        mx = fmaxf(mx, __shfl_xor(mx, 32));
        float s = 0.f;
#pragma unroll
        for (int rt = 0; rt < 4; ++rt)
#pragma unroll
            for (int j = 0; j < 4; ++j) {
                float e = __expf(stc[rt][j] - mx);
                stc[rt][j] = e;
                s += e;
            }
        s += __shfl_xor(s, 16);
        s += __shfl_xor(s, 32);
        float inv = 1.f / s;
        unsigned pp[4][2];
#pragma unroll
        for (int rt = 0; rt < 4; ++rt) {
            pp[rt][0] = pack2(stc[rt][0] * inv, stc[rt][1] * inv);
            pp[rt][1] = pack2(stc[rt][2] * inv, stc[rt][3] * inv);
        }
        ap[c][0] = bfly4(pp[0][0], pp[0][1], pp[1][0], pp[1][1], lane);
        ap[c][1] = bfly4(pp[2][0], pp[2][1], pp[3][0], pp[3][1], lane);
    }

    // ---- V fragments (A-operand of swapped PV): lane r16 = d ----
    bf16x8 av[2][2];
#pragma unroll
    for (int dt = 0; dt < 2; ++dt)
#pragma unroll
        for (int ks = 0; ks < 2; ++ks)
            av[dt][ks] = bfly4(vp[2 * ks][dt][0], vp[2 * ks][dt][1],
                               vp[2 * ks + 1][dt][0], vp[2 * ks + 1][dt][1],
                               lane);

    // ---- PV (swapped): o2[dt][mq] elem j = out[q mq*16+r16][d dt*16+g*4+j]
    f32x4 o2[2][4];
#pragma unroll
    for (int dt = 0; dt < 2; ++dt)
#pragma unroll
        for (int mq = 0; mq < 4; ++mq) o2[dt][mq] = zero4;
#pragma unroll
    for (int ks = 0; ks < 2; ++ks)
#pragma unroll
        for (int dt = 0; dt < 2; ++dt)
#pragma unroll
            for (int mq = 0; mq < 4; ++mq)
                o2[dt][mq] = mfma16(av[dt][ks], ap[mq][ks], o2[dt][mq]);

    // contiguous us4 scatter into AO
#pragma unroll
    for (int dt = 0; dt < 2; ++dt)
#pragma unroll
        for (int mq = 0; mq < 4; ++mq) {
            us4 pk = { f2bf(o2[dt][mq][0]), f2bf(o2[dt][mq][1]),
                       f2bf(o2[dt][mq][2]), f2bf(o2[dt][mq][3]) };
            *reinterpret_cast<us4*>(
                &sm[AO + (mq * 16 + r16) * 264 + h * 32 + dt * 16 + g * 4]) = pk;
        }
    __syncthreads();                                   // B1: AO ready

    // ---- Phase 3: proj GEMM, wave owns output cols [32w, 32w+32) ----
    f32x4 c3[4][2];
#pragma unroll
    for (int mt = 0; mt < 4; ++mt)
#pragma unroll
        for (int nt = 0; nt < 2; ++nt) c3[mt][nt] = zero4;
#pragma unroll
    for (int ks = 0; ks < 8; ++ks) {
        bf16x8 a3[4];
#pragma unroll
        for (int mt = 0; mt < 4; ++mt)
            a3[mt] = lds8(&sm[AO + (mt * 16 + r16) * 264 + ks * 32 + g * 8]);
#pragma unroll
        for (int nt = 0; nt < 2; ++nt) {
            bf16x8 b3 = *reinterpret_cast<const bf16x8*>(
                proj_wb + (wid * 32 + nt * 16 + r16) * 256 + ks * 32 + g * 8);
#pragma unroll
            for (int mt = 0; mt < 4; ++mt)
                c3[mt][nt] = mfma16(a3[mt], b3, c3[mt][nt]);
        }
    }
    float* og = out + (size_t)win * 16384;
#pragma unroll
    for (int nt = 0; nt < 2; ++nt) {
        int n = wid * 32 + nt * 16 + r16;
        float pb = proj_b[n];
#pragma unroll
        for (int mt = 0; mt < 4; ++mt)
#pragma unroll
            for (int j = 0; j < 4; ++j)
                og[(size_t)(mt * 16 + g * 4 + j) * 256 + n] = c3[mt][nt][j] + pb;
    }
}

extern "C" void kernel_launch(void* const* d_in, const int* in_sizes, int n_in,
                              void* d_out, int out_size, void* d_ws, size_t ws_size,
                              hipStream_t stream) {
    const float* x          = (const float*)d_in[0];
    const float* qkv_w      = (const float*)d_in[1];
    const float* qkv_b      = (const float*)d_in[2];
    const float* proj_w     = (const float*)d_in[3];
    const float* proj_b     = (const float*)d_in[4];
    const float* bias_table = (const float*)d_in[5];
    const int*   rel_index  = (const int*)d_in[6];

    unsigned short* qkv_wb  = (unsigned short*)d_ws;
    unsigned short* proj_wb = (unsigned short*)((char*)d_ws + 393216);
    float* biasF            = (float*)((char*)d_ws + 524288);

    prep_kernel<<<256, 256, 0, stream>>>(qkv_w, proj_w, bias_table, rel_index,
                                         qkv_wb, proj_wb, biasF);
    win_attn_kernel<<<4096, 512, 0, stream>>>(x, qkv_b, proj_b, qkv_wb, proj_wb,
                                              biasF, (float*)d_out);
}